// Round 10
// baseline (423.555 us; speedup 1.0000x reference)
//
#include <hip/hip_runtime.h>

typedef __bf16 bf16x8 __attribute__((ext_vector_type(8)));
typedef float f32x4 __attribute__((ext_vector_type(4)));
typedef float fv4 __attribute__((ext_vector_type(4)));

#define B_ 8
#define T_ 2048
#define C_ 1024
#define H_ 128

// ---------------- prep: W[1024][128] fp32 -> Wt[wsel][128][1024] bf16 ----------------
__global__ __launch_bounds__(256) void prep_kernel(
    const float* __restrict__ Wq, const float* __restrict__ Wk,
    const float* __restrict__ Wv, __bf16* __restrict__ Wt)
{
  __shared__ __bf16 ldsT[128 * 136];
  const int tid = threadIdx.x;
  const int k0 = blockIdx.x * 128;
  const int wsel = blockIdx.y;
  const float* W = wsel == 0 ? Wq : (wsel == 1 ? Wk : Wv);
#pragma unroll
  for (int i = 0; i < 16; ++i) {
    int fidx = tid + 256 * i;
    int k = fidx >> 5, h4 = (fidx & 31) << 2;
    fv4 w = *(const fv4*)(W + (size_t)(k0 + k) * H_ + h4);
#pragma unroll
    for (int j = 0; j < 4; ++j) ldsT[(h4 + j) * 136 + k] = (__bf16)w[j];
  }
  __syncthreads();
#pragma unroll
  for (int i = 0; i < 8; ++i) {
    int sidx = tid + 256 * i;
    int h = sidx >> 4, c8 = (sidx & 15) << 3;
    *(bf16x8*)(Wt + (size_t)wsel * H_ * C_ + (size_t)h * C_ + k0 + c8) =
        *(const bf16x8*)&ldsT[h * 136 + c8];
  }
}

// ---------------- fused QKV projection: BARRIER-FREE main loop ----------------
// grid 512 (32-row x-tiles), block 256 (4 independent waves). Each lane loads
// its own MFMA fragments direct from global (A: x fp32->bf16 inline, 32B/lane
// contiguous; B: Wt bf16 16B/lane). No LDS staging => no s_barrier => the
// compiler's vmcnt(0)-before-barrier drain (r8/r9 stall) is gone; depth-2
// register rotation pipelines freely. Single barrier only in V^T epilogue.
__global__ __launch_bounds__(256, 2) void proj_kernel(
    const float* __restrict__ x, const __bf16* __restrict__ Wt,
    __bf16* __restrict__ Qw, __bf16* __restrict__ Kw, __bf16* __restrict__ Vtw)
{
  __shared__ __align__(16) __bf16 ldsT[128 * 40];  // V^T transpose only
  const int tid = threadIdx.x;
  const int wave = tid >> 6, lane = tid & 63;
  const int q4 = lane >> 4, l16 = lane & 15;
  const int bt0 = blockIdx.x * 32;

  const float* xb0 = x + (size_t)(bt0 + l16) * C_ + q4 * 8;
  const float* xb1 = xb0 + 16 * C_;
  const __bf16* wb = Wt + (size_t)(wave * 96 + l16) * C_ + q4 * 8;

  const f32x4 zero4 = {0.f, 0.f, 0.f, 0.f};
  f32x4 acc[2][6];
#pragma unroll
  for (int mt = 0; mt < 2; ++mt)
#pragma unroll
    for (int nt = 0; nt < 6; ++nt) acc[mt][nt] = zero4;

  // depth-2 register pipeline
  fv4 xa[2][2][2];   // [slot][mt][half]
  bf16x8 wp[2][6];
#pragma unroll
  for (int s = 0; s < 2; ++s) {
    const int kb = s * 32;
    xa[s][0][0] = *(const fv4*)(xb0 + kb);
    xa[s][0][1] = *(const fv4*)(xb0 + kb + 4);
    xa[s][1][0] = *(const fv4*)(xb1 + kb);
    xa[s][1][1] = *(const fv4*)(xb1 + kb + 4);
#pragma unroll
    for (int nt = 0; nt < 6; ++nt)
      wp[s][nt] = *(const bf16x8*)(wb + (size_t)nt * 16 * C_ + kb);
  }

  for (int c = 0; c < 32; ++c) {
    const int s = c & 1;
    bf16x8 af[2];
#pragma unroll
    for (int mt = 0; mt < 2; ++mt)
#pragma unroll
      for (int j = 0; j < 4; ++j) {
        af[mt][j] = (__bf16)xa[s][mt][0][j];
        af[mt][4 + j] = (__bf16)xa[s][mt][1][j];
      }
    bf16x8 bcur[6];
#pragma unroll
    for (int nt = 0; nt < 6; ++nt) bcur[nt] = wp[s][nt];
    // prefetch chunk c+2 into slot s (no barrier anywhere to drain it)
    const int kn = (c + 2 < 32) ? (c + 2) * 32 : c * 32;
    xa[s][0][0] = *(const fv4*)(xb0 + kn);
    xa[s][0][1] = *(const fv4*)(xb0 + kn + 4);
    xa[s][1][0] = *(const fv4*)(xb1 + kn);
    xa[s][1][1] = *(const fv4*)(xb1 + kn + 4);
#pragma unroll
    for (int nt = 0; nt < 6; ++nt)
      wp[s][nt] = *(const bf16x8*)(wb + (size_t)nt * 16 * C_ + kn);
#pragma unroll
    for (int nt = 0; nt < 6; ++nt)
#pragma unroll
      for (int mt = 0; mt < 2; ++mt)
        acc[mt][nt] = __builtin_amdgcn_mfma_f32_16x16x32_bf16(af[mt], bcur[nt], acc[mt][nt], 0, 0, 0);
  }

  // epilogue. C/D: row=q4*4+r, col=l16 (HW-validated)
  const int b = bt0 >> 11, t0 = bt0 & (T_ - 1);
#pragma unroll
  for (int mt = 0; mt < 2; ++mt)
#pragma unroll
    for (int nt = 0; nt < 6; ++nt) {
      int gcol = wave * 96 + nt * 16 + l16;
#pragma unroll
      for (int r = 0; r < 4; ++r) {
        int row = bt0 + mt * 16 + q4 * 4 + r;
        float v = acc[mt][nt][r];
        if (gcol < 128) Qw[(size_t)row * H_ + gcol] = (__bf16)v;
        else if (gcol < 256) Kw[(size_t)row * H_ + (gcol - 128)] = (__bf16)v;
        else ldsT[(gcol - 256) * 40 + (mt * 16 + q4 * 4 + r)] = (__bf16)v;
      }
    }
  __syncthreads();
#pragma unroll
  for (int i = 0; i < 2; ++i) {
    int idx = tid + 256 * i;
    int h = idx >> 2, t8 = (idx & 3) << 3;
    *(bf16x8*)(Vtw + ((size_t)b * H_ + h) * T_ + t0 + t8) =
        *(const bf16x8*)&ldsT[h * 40 + t8];
  }
}

// ---------------- split-K causal flash attention: BARRIER-FREE ----------------
// grid (80, 8), block 256 (4 independent waves). K/V fragments loaded per-wave
// direct from global (L2-resident: 0.5 MB K + 0.5 MB Vt per batch). Only LDS
// is the wave-private P round-trip (lgkmcnt, no barrier). Zero __syncthreads.
__global__ __launch_bounds__(256, 2) void attn_split(
    const __bf16* __restrict__ Q, const __bf16* __restrict__ K,
    const __bf16* __restrict__ Vt, __bf16* __restrict__ PO,
    float* __restrict__ Pl, float* __restrict__ out)
{
  __shared__ __align__(16) __bf16 ldsP[4][16 * 72];
  const int tid = threadIdx.x;
  const int wave = tid >> 6, lane = tid & 63;
  const int q4 = lane >> 4, l16 = lane & 15;
  const int b = blockIdx.y;
  int rem = blockIdx.x, qb = 0;
  while (rem >= (qb >> 3) + 1) { rem -= (qb >> 3) + 1; ++qb; }
  const int c = rem;
  const int tstart = c << 3;
  const int tend = min(tstart + 8, qb + 1);
  const int nch = (qb >> 3) + 1;
  const int qw = qb * 64 + wave * 16;
  const __bf16* Qb = Q + (size_t)b * T_ * H_;
  const __bf16* Kb = K + (size_t)b * T_ * H_;
  const __bf16* Vb = Vt + (size_t)b * H_ * T_;
  __bf16* ldsPw = &ldsP[wave][0];

  bf16x8 qf[4];
#pragma unroll
  for (int kc = 0; kc < 4; ++kc)
    qf[kc] = *(const bf16x8*)(Qb + (size_t)(qw + l16) * H_ + kc * 32 + q4 * 8);

  const f32x4 zero4 = {0.f, 0.f, 0.f, 0.f};
  f32x4 o[8];
#pragma unroll
  for (int nt = 0; nt < 8; ++nt) o[nt] = zero4;
  float lsum[4] = {0.f, 0.f, 0.f, 0.f};

  for (int t = tstart; t < tend; ++t) {
    const int kv0 = t << 6;
    // direct-to-register K and V fragments (issue all; V consumed late)
    bf16x8 kf[4][4];
#pragma unroll
    for (int nt = 0; nt < 4; ++nt)
#pragma unroll
      for (int kc = 0; kc < 4; ++kc)
        kf[nt][kc] = *(const bf16x8*)(Kb + (size_t)(kv0 + nt * 16 + l16) * H_ + kc * 32 + q4 * 8);
    bf16x8 vf[8][2];
#pragma unroll
    for (int nt = 0; nt < 8; ++nt)
#pragma unroll
      for (int k2 = 0; k2 < 2; ++k2)
        vf[nt][k2] = *(const bf16x8*)(Vb + (size_t)(nt * 16 + l16) * T_ + kv0 + k2 * 32 + q4 * 8);

    f32x4 s[4];
#pragma unroll
    for (int nt = 0; nt < 4; ++nt) s[nt] = zero4;
#pragma unroll
    for (int nt = 0; nt < 4; ++nt)
#pragma unroll
      for (int kc = 0; kc < 4; ++kc)
        s[nt] = __builtin_amdgcn_mfma_f32_16x16x32_bf16(qf[kc], kf[nt][kc], s[nt], 0, 0, 0);

    if (t == qb) {  // diagonal tile: causal mask
#pragma unroll
      for (int r = 0; r < 4; ++r) {
        const int grow = qw + q4 * 4 + r;
#pragma unroll
        for (int nt = 0; nt < 4; ++nt) {
          int col = kv0 + nt * 16 + l16;
          float p = (col <= grow) ? __expf(s[nt][r] * 0.08838834764831845f) : 0.f;
          lsum[r] += p;
          ldsPw[(q4 * 4 + r) * 72 + nt * 16 + l16] = (__bf16)p;
        }
      }
    } else {
#pragma unroll
      for (int r = 0; r < 4; ++r)
#pragma unroll
        for (int nt = 0; nt < 4; ++nt) {
          float p = __expf(s[nt][r] * 0.08838834764831845f);
          lsum[r] += p;
          ldsPw[(q4 * 4 + r) * 72 + nt * 16 + l16] = (__bf16)p;
        }
    }
#pragma unroll
    for (int k2 = 0; k2 < 2; ++k2) {
      bf16x8 pf = *(const bf16x8*)&ldsPw[l16 * 72 + k2 * 32 + q4 * 8];
#pragma unroll
      for (int nt = 0; nt < 8; ++nt)
        o[nt] = __builtin_amdgcn_mfma_f32_16x16x32_bf16(pf, vf[nt][k2], o[nt], 0, 0, 0);
    }
  }

  float lred[4];
#pragma unroll
  for (int r = 0; r < 4; ++r) {
    float l = lsum[r];
    l += __shfl_xor(l, 1);
    l += __shfl_xor(l, 2);
    l += __shfl_xor(l, 4);
    l += __shfl_xor(l, 8);
    lred[r] = l;
  }

  if (nch == 1) {
#pragma unroll
    for (int r = 0; r < 4; ++r) lred[r] = 1.f / lred[r];
#pragma unroll
    for (int nt = 0; nt < 8; ++nt)
#pragma unroll
      for (int r = 0; r < 4; ++r) {
        int row = qw + q4 * 4 + r;
        out[((size_t)b * T_ + row) * H_ + nt * 16 + l16] = o[nt][r] * lred[r];
      }
  } else {
    const int slot = b * 80 + qb + max(qb - 8, 0) + max(qb - 16, 0) + max(qb - 24, 0) + c;
    __bf16* POs = PO + (size_t)slot * 8192;
#pragma unroll
    for (int nt = 0; nt < 8; ++nt)
#pragma unroll
      for (int r = 0; r < 4; ++r)
        POs[(wave * 16 + q4 * 4 + r) * 128 + nt * 16 + l16] = (__bf16)o[nt][r];
    if (l16 == 0)
#pragma unroll
      for (int r = 0; r < 4; ++r)
        Pl[slot * 64 + wave * 16 + q4 * 4 + r] = lred[r];
  }
}

// ---------------- combine partials (qb >= 8), 16 rows/block ----------------
__global__ __launch_bounds__(256) void attn_combine(
    const __bf16* __restrict__ PO, const float* __restrict__ Pl,
    float* __restrict__ out)
{
  const int qb = 8 + (blockIdx.x >> 2);
  const int seg = blockIdx.x & 3;
  const int b = blockIdx.y;
  const int nch = (qb >> 3) + 1;
  const int slot0 = b * 80 + qb + max(qb - 8, 0) + max(qb - 16, 0) + max(qb - 24, 0);
  const int tid = threadIdx.x;
  const int rloc = seg * 16 + (tid >> 4);
  const int col8 = (tid & 15) << 3;
  float oacc[8] = {0.f};
  float lacc = 0.f;
  for (int cc = 0; cc < nch; ++cc) {
    const int slot = slot0 + cc;
    lacc += Pl[slot * 64 + rloc];
    bf16x8 v = *(const bf16x8*)(PO + (size_t)slot * 8192 + rloc * 128 + col8);
#pragma unroll
    for (int j = 0; j < 8; ++j) oacc[j] += (float)v[j];
  }
  const float inv = 1.f / lacc;
  float* op = out + ((size_t)b * T_ + qb * 64 + rloc) * H_ + col8;
  fv4 v0, v1;
#pragma unroll
  for (int j = 0; j < 4; ++j) { v0[j] = oacc[j] * inv; v1[j] = oacc[4 + j] * inv; }
  *(fv4*)op = v0;
  *(fv4*)(op + 4) = v1;
}

// ---------------- fallback mono attention (HW-validated r7) ----------------
__global__ __launch_bounds__(256) void attn_mono(
    const __bf16* __restrict__ Q, const __bf16* __restrict__ K,
    const __bf16* __restrict__ Vt, float* __restrict__ out)
{
  __shared__ __align__(16) __bf16 ldsK[64 * 136];
  __shared__ __align__(16) __bf16 ldsV[128 * 72];
  __shared__ __align__(16) __bf16 ldsP[4][16 * 72];
  const int tid = threadIdx.x;
  const int wave = tid >> 6, lane = tid & 63;
  const int q4 = lane >> 4, l16 = lane & 15;
  const int qb = blockIdx.x, b = blockIdx.y;
  const int qw = qb * 64 + wave * 16;
  const __bf16* Qb = Q + (size_t)b * T_ * H_;
  const __bf16* Kb = K + (size_t)b * T_ * H_;
  const __bf16* Vb = Vt + (size_t)b * H_ * T_;
  __bf16* ldsPw = &ldsP[wave][0];

  bf16x8 qf[4];
#pragma unroll
  for (int kc = 0; kc < 4; ++kc)
    qf[kc] = *(const bf16x8*)(Qb + (size_t)(qw + l16) * H_ + kc * 32 + q4 * 8);

  const f32x4 zero4 = {0.f, 0.f, 0.f, 0.f};
  f32x4 o[8];
#pragma unroll
  for (int nt = 0; nt < 8; ++nt) o[nt] = zero4;
  float lsum[4] = {0.f, 0.f, 0.f, 0.f};
  const int ntile = qb + 1;

  for (int t = 0; t < ntile; ++t) {
    const int kv0 = t << 6;
#pragma unroll
    for (int i = 0; i < 4; ++i) {
      int idx = tid + 256 * i;
      int krow = idx >> 4, kcol8 = (idx & 15) << 3;
      *(bf16x8*)&ldsK[krow * 136 + kcol8] =
          *(const bf16x8*)(Kb + (size_t)(kv0 + krow) * H_ + kcol8);
      int vrow = idx >> 3, vcol8 = (idx & 7) << 3;
      *(bf16x8*)&ldsV[vrow * 72 + vcol8] =
          *(const bf16x8*)(Vb + (size_t)vrow * T_ + kv0 + vcol8);
    }
    __syncthreads();
    f32x4 s[4];
#pragma unroll
    for (int nt = 0; nt < 4; ++nt) s[nt] = zero4;
#pragma unroll
    for (int nt = 0; nt < 4; ++nt)
#pragma unroll
      for (int kc = 0; kc < 4; ++kc) {
        bf16x8 kf = *(const bf16x8*)&ldsK[(nt * 16 + l16) * 136 + kc * 32 + q4 * 8];
        s[nt] = __builtin_amdgcn_mfma_f32_16x16x32_bf16(qf[kc], kf, s[nt], 0, 0, 0);
      }
#pragma unroll
    for (int r = 0; r < 4; ++r) {
      const int grow = qw + q4 * 4 + r;
#pragma unroll
      for (int nt = 0; nt < 4; ++nt) {
        int col = kv0 + nt * 16 + l16;
        float p = (col <= grow) ? __expf(s[nt][r] * 0.08838834764831845f) : 0.f;
        lsum[r] += p;
        ldsPw[(q4 * 4 + r) * 72 + nt * 16 + l16] = (__bf16)p;
      }
    }
#pragma unroll
    for (int k2 = 0; k2 < 2; ++k2) {
      bf16x8 pf = *(const bf16x8*)&ldsPw[l16 * 72 + k2 * 32 + q4 * 8];
#pragma unroll
      for (int nt = 0; nt < 8; ++nt) {
        bf16x8 vf = *(const bf16x8*)&ldsV[(nt * 16 + l16) * 72 + k2 * 32 + q4 * 8];
        o[nt] = __builtin_amdgcn_mfma_f32_16x16x32_bf16(pf, vf, o[nt], 0, 0, 0);
      }
    }
    __syncthreads();
  }
  float rinv[4];
#pragma unroll
  for (int r = 0; r < 4; ++r) {
    float l = lsum[r];
    l += __shfl_xor(l, 1);
    l += __shfl_xor(l, 2);
    l += __shfl_xor(l, 4);
    l += __shfl_xor(l, 8);
    rinv[r] = 1.f / l;
  }
#pragma unroll
  for (int nt = 0; nt < 8; ++nt)
#pragma unroll
    for (int r = 0; r < 4; ++r) {
      int row = qw + q4 * 4 + r;
      out[((size_t)b * T_ + row) * H_ + nt * 16 + l16] = o[nt][r] * rinv[r];
    }
}

extern "C" void kernel_launch(void* const* d_in, const int* in_sizes, int n_in,
                              void* d_out, int out_size, void* d_ws, size_t ws_size,
                              hipStream_t stream) {
  const float* x  = (const float*)d_in[0];
  const float* Wq = (const float*)d_in[1];
  const float* Wk = (const float*)d_in[2];
  const float* Wv = (const float*)d_in[3];
  __bf16* ws = (__bf16*)d_ws;
  __bf16* Qw  = ws;                             // [B*T][H]   4 MB
  __bf16* Kw  = ws + (size_t)B_ * T_ * H_;      // [B*T][H]   4 MB
  __bf16* Vtw = ws + (size_t)2 * B_ * T_ * H_;  // [B][H][T]  4 MB
  __bf16* Wt  = ws + (size_t)3 * B_ * T_ * H_;  // [3][H][C]  0.75 MB
  const size_t bf16_elems = 6684672;            // 13,369,344 B
  __bf16* PO = ws + bf16_elems;                 // 640 x 8192 bf16 = 10.5 MB
  float* Pl = (float*)(ws + bf16_elems + (size_t)640 * 8192);  // 640 x 64 fp32
  const size_t need = bf16_elems * 2 + (size_t)640 * 8192 * 2 + (size_t)640 * 64 * 4;
  float* out = (float*)d_out;

  prep_kernel<<<dim3(8, 3), 256, 0, stream>>>(Wq, Wk, Wv, Wt);
  proj_kernel<<<512, 256, 0, stream>>>(x, Wt, Qw, Kw, Vtw);
  if (ws_size >= need) {
    attn_split<<<dim3(80, 8), 256, 0, stream>>>(Qw, Kw, Vtw, PO, Pl, out);
    attn_combine<<<dim3(96, 8), 256, 0, stream>>>(PO, Pl, out);
  } else {
    attn_mono<<<dim3(32, 8), 256, 0, stream>>>(Qw, Kw, Vtw, out);
  }
}